// Round 18
// baseline (194.000 us; speedup 1.0000x reference)
//
#include <hip/hip_runtime.h>

#define TT 512

typedef _Float16 f16x8 __attribute__((ext_vector_type(8)));
typedef float f32x4 __attribute__((ext_vector_type(4)));

__device__ __forceinline__ float fast_exp2(float v) { return __builtin_amdgcn_exp2f(v); }
__device__ __forceinline__ float fast_rcp(float v)  { return __builtin_amdgcn_rcpf(v); }

template <int CTRL>
__device__ __forceinline__ float dppmovf(float v) {
    return __builtin_bit_cast(float, (unsigned)__builtin_amdgcn_update_dpp(
        0, (int)__builtin_bit_cast(unsigned, v), CTRL, 0xF, 0xF, true));
}
#define DPP_ROR8 0x128  // row_ror:8 == lane^8 within 16-lane rows

__global__ __launch_bounds__(64, 2) void lstm_ls2_kernel(
    const float* __restrict__ x,     // [B, T, 1]
    const float* __restrict__ wih,   // [128, 1]
    const float* __restrict__ whh,   // [128, 32]
    const float* __restrict__ bih,   // [128]
    const float* __restrict__ bhh,   // [128]
    const float* __restrict__ fc1w,  // [16, 32]
    const float* __restrict__ fc1b,  // [16]
    const float* __restrict__ fc2w,  // [1, 16]
    const float* __restrict__ fc2b,  // [1]
    float* __restrict__ out)         // [B, 1]
{
    __shared__ float lds_xT[TT + 2][2];   // x transposed [t][batch 0..1]; rows TT,TT+1 zeroed
    __shared__ float lds_hf[2][32];       // final h f32 for MLP head

    const int lane = threadIdx.x;         // single wave per block
    const int b0 = blockIdx.x * 2;        // 2 real batches per block
    const int c  = lane & 15;             // MFMA col
    const int cb = c & 1;                 // real batch
    const int g  = c >> 1;                // group 0..7: owns unit 4q + (g&3) + 16*(g>>2)
    const int q  = lane >> 4;             // k-group / C row-group
    const int r  = g & 3;                 // owned acc row
    const int p  = g >> 2;                // owned p (0: unit<16, 1: unit>=16)

    // ---- stage x rows b0,b0+1 transposed into LDS ----
    {
        const int rb = lane >> 5;         // batch 0..1
        const int m  = lane & 31;
        const float4* xr = reinterpret_cast<const float4*>(x + (size_t)(b0 + rb) * TT);
#pragma unroll
        for (int it = 0; it < 4; ++it) {
            const int idx = it * 32 + m;  // float4 index 0..127
            const float4 v = xr[idx];
            const int t0 = idx * 4;
            lds_xT[t0 + 0][rb] = v.x;
            lds_xT[t0 + 1][rb] = v.y;
            lds_xT[t0 + 2][rb] = v.z;
            lds_xT[t0 + 3][rb] = v.w;
        }
        if (lane < 4) lds_xT[TT + (lane >> 1)][lane & 1] = 0.0f;
    }

    const float NK  = -1.4426950408889634f;   // -log2(e)
    const float NK2 = -2.8853900817779268f;   // -2*log2(e)

    // ---- A fragments, GLOBAL sigma k-order: k-slot 8q+2s+pp <-> unit 4q+s+16pp ----
    f16x8 afrag[8];
#pragma unroll
    for (int n = 0; n < 8; ++n) {
        const float s = (n == 4 || n == 5) ? NK2 : NK;
        const float* src = whh + (n * 16 + c) * 32;
        f16x8 a;
#pragma unroll
        for (int j = 0; j < 8; ++j)
            a[j] = (_Float16)(s * src[4 * q + (j >> 1) + 16 * (j & 1)]);
        afrag[n] = a;
    }

    // ---- scaled wih / bias for the OWN gate rows: gg = (2gt+p)*16 + 4q + r ----
    float wq[4], bq[4];
#pragma unroll
    for (int gt = 0; gt < 4; ++gt) {
        const float s = (gt == 2) ? NK2 : NK;
        const int gg = (2 * gt + p) * 16 + q * 4 + r;
        wq[gt] = s * wih[gg];
        bq[gt] = s * (bih[gg] + bhh[gg]);
    }

    // bpermute byte-addresses: bfrag word s sourced from lane 16q + 2s + cb
    const int ba0 = 4 * (16 * q + 0 + cb);
    const int ba1 = 4 * (16 * q + 2 + cb);
    const int ba2 = 4 * (16 * q + 4 + cb);
    const int ba3 = 4 * (16 * q + 6 + cb);

    f16x8 bfrag;
#pragma unroll
    for (int j = 0; j < 8; ++j) bfrag[j] = (_Float16)0.0f;

    float cs = 0.0f;                      // c-state for the single owned unit
    const f32x4 zero4 = {0.0f, 0.0f, 0.0f, 0.0f};
    const bool rl = (r & 1) != 0;
    const bool rh = (r & 2) != 0;
    const bool pp = (p != 0);

    float xv = lds_xT[0][cb];             // same-wave DS ordering; no barrier needed

#pragma unroll 1
    for (int t = 0; t < TT; ++t) {
        f32x4 acc[8];
#pragma unroll
        for (int n = 0; n < 8; ++n)
            acc[n] = __builtin_amdgcn_mfma_f32_16x16x32_f16(afrag[n], bfrag, zero4, 0, 0, 0);

        const float xnext = lds_xT[t + 1][cb];

        // extract own row r from the 8 acc tiles (3 cndmask each), then p-select per gate
        float ex[8];
#pragma unroll
        for (int n = 0; n < 8; ++n) {
            const float lo = rl ? acc[n][1] : acc[n][0];
            const float hi = rl ? acc[n][3] : acc[n][2];
            ex[n] = rh ? hi : lo;
        }
        const float vi = __builtin_fmaf(xv, wq[0], bq[0]) + (pp ? ex[1] : ex[0]);
        const float vf = __builtin_fmaf(xv, wq[1], bq[1]) + (pp ? ex[3] : ex[2]);
        const float vg = __builtin_fmaf(xv, wq[2], bq[2]) + (pp ? ex[5] : ex[4]);
        const float vo = __builtin_fmaf(xv, wq[3], bq[3]) + (pp ? ex[7] : ex[6]);

        // single cell update
        const float ei = fast_exp2(vi);
        const float ef = fast_exp2(vf);
        const float eg = fast_exp2(vg);
        const float eo = fast_exp2(vo);
        const float P  = (1.0f + ei) * (1.0f + eg);
        const float Bf = 1.0f + ef;
        const float N  = __builtin_fmaf(cs, P, (1.0f - eg) * Bf);
        const float cn = N * fast_rcp(P * Bf);
        cs = cn;
        const float ec = fast_exp2(NK2 * cn);
        const float hv = (1.0f - ec) * fast_rcp((1.0f + eo) * (1.0f + ec));

        // merge p-partner (lane^8) and pack (p0 -> low half)
        const float ho = dppmovf<DPP_ROR8>(hv);
        const float hlo = pp ? ho : hv;
        const float hhi = pp ? hv : ho;
        const int w = (int)__builtin_bit_cast(unsigned, __builtin_amdgcn_cvt_pkrtz(hlo, hhi));

        // gather bfrag words via 4 static bpermutes
        uint4 bw;
        bw.x = (unsigned)__builtin_amdgcn_ds_bpermute(ba0, w);
        bw.y = (unsigned)__builtin_amdgcn_ds_bpermute(ba1, w);
        bw.z = (unsigned)__builtin_amdgcn_ds_bpermute(ba2, w);
        bw.w = (unsigned)__builtin_amdgcn_ds_bpermute(ba3, w);
        bfrag = __builtin_bit_cast(f16x8, bw);

        xv = xnext;
    }

    // ---- final h to LDS: bfrag[2s+pp'] = h(unit 4q+s+16pp') of batch cb ----
    if (c < 2) {
#pragma unroll
        for (int j = 0; j < 8; ++j)
            lds_hf[c][4 * q + (j >> 1) + 16 * (j & 1)] = (float)bfrag[j];
    }

    // same-wave write->read, in order; no barrier needed
    const int bat = lane >> 5;            // 32 lanes per batch
    const int m   = lane & 31;            // fc1 row (m<16 active)
    float val = 0.0f;
    if (m < 16) {
        float s = fc1b[m];
        const float* fw = fc1w + m * 32;
#pragma unroll 8
        for (int u = 0; u < 32; ++u) s = __builtin_fmaf(lds_hf[bat][u], fw[u], s);
        val = fmaxf(s, 0.0f) * fc2w[m];
    }
    val += __shfl_xor(val, 1);
    val += __shfl_xor(val, 2);
    val += __shfl_xor(val, 4);
    val += __shfl_xor(val, 8);
    if (m == 0) out[b0 + bat] = val + fc2b[0];
}

extern "C" void kernel_launch(void* const* d_in, const int* in_sizes, int n_in,
                              void* d_out, int out_size, void* d_ws, size_t ws_size,
                              hipStream_t stream) {
    const float* x    = (const float*)d_in[0];
    const float* wih  = (const float*)d_in[1];
    const float* whh  = (const float*)d_in[2];
    const float* bih  = (const float*)d_in[3];
    const float* bhh  = (const float*)d_in[4];
    const float* fc1w = (const float*)d_in[5];
    const float* fc1b = (const float*)d_in[6];
    const float* fc2w = (const float*)d_in[7];
    const float* fc2b = (const float*)d_in[8];
    float* out = (float*)d_out;

    const int B = out_size;               // 4096
    dim3 grid(B / 2), block(64);          // 2048 one-wave chains -> 2 per SIMD
    hipLaunchKernelGGL(lstm_ls2_kernel, grid, block, 0, stream,
                       x, wih, whh, bih, bhh, fc1w, fc1b, fc2w, fc2b, out);
}